// Round 11
// baseline (194.074 us; speedup 1.0000x reference)
//
#include <hip/hip_runtime.h>

#define DZ 512
#define DT 66048
#define NP 2064        // 32-col pairs
#define PROW 516       // padded floats per panel row (2064 B, kills 2KB-stride conflicts)
#define SV_JITTER 1e-4f

typedef __attribute__((ext_vector_type(8))) short bf8;
typedef __attribute__((ext_vector_type(4))) float f4;

__device__ __forceinline__ short f2bf(float f) {
  unsigned u = __builtin_bit_cast(unsigned, f);
  return (short)((u + 0x7FFFu + ((u >> 16) & 1u)) >> 16);
}

__device__ __forceinline__ bf8 cvt8(float4 a, float4 b) {
  bf8 r = { f2bf(a.x), f2bf(a.y), f2bf(a.z), f2bf(a.w),
            f2bf(b.x), f2bf(b.y), f2bf(b.z), f2bf(b.w) };
  return r;
}

// tril/jitter cvt: element t has k-index kbase+t
__device__ __forceinline__ bf8 cvt8_tril(float4 x, float4 y, int kbase, int diag) {
  float v[8] = {x.x, x.y, x.z, x.w, y.x, y.y, y.z, y.w};
  bf8 r;
  #pragma unroll
  for (int t = 0; t < 8; ++t) {
    int k = kbase + t;
    float val = (k < diag) ? v[t] : ((k == diag) ? v[t] + SV_JITTER : 0.f);
    r[t] = f2bf(val);
  }
  return r;
}

// 256 blocks (1/CU) x 1024 threads (16 waves = 4/SIMD, VGPR cap 128).
// Block processes pairs p = b + 256*js (32 cols each). Per round the pair's
// B panel -- a CONTIGUOUS 64KB region of Lyz/Lz -- is cooperatively staged
// (16 fully-sequential dwordx4 per thread-set) into a double-buffered padded
// fp32 LDS panel. A (eps_z) lives in registers: af[16] loaded once (L2-hot).
// Compute phase: ds_read + cvt + MFMA only, zero global loads. One barrier
// per round; stage loads issued before compute, ds_write after (write-late).
// Waves: grp=wv>>3 picks the 16-col tile of the pair, wsg=wv&7 the 16-sample
// group. acc layout per mfma_f32_16x16x32_bf16: col=lane&15, row=4*(lane>>4)+reg.
__global__ __launch_bounds__(1024, 4)
void sv_kernel(const float* __restrict__ mv, const float* __restrict__ Lz,
               const float* __restrict__ Ly, const float* __restrict__ Lyz,
               const float* __restrict__ eps, float* __restrict__ out) {
  __shared__ float Bp[2][32 * PROW];  // 2 x 64.5 KB = 129 KB

  const int tid = threadIdx.x;
  const int lane = tid & 63;
  const int wv = tid >> 6;   // 0..15
  const int lcol = lane & 15;
  const int q = lane >> 4;
  const int grp = wv >> 3;   // which 16-col tile of the pair
  const int wsg = wv & 7;    // sample group (rows 16*wsg..+15)
  const int b = blockIdx.x;

  float4 sv[4];  // staged floats (16 VGPR), live across one compute phase
  auto stage_issue = [&](int p) {
    const float4* s4 = (p < 16)
        ? (const float4*)(Lz + (size_t)p * 32 * DZ)
        : (const float4*)(Lyz + (size_t)(p - 16) * 32 * DZ);
    #pragma unroll
    for (int i = 0; i < 4; ++i) sv[i] = s4[i * 1024 + tid];
  };
  auto stage_write = [&](float* buf) {
    #pragma unroll
    for (int i = 0; i < 4; ++i) {
      const int f = i * 1024 + tid;  // float4 index within 64KB panel
      const int row = f >> 7;        // 128 float4 per 2KB row
      const int c4 = f & 127;
      *(float4*)(buf + row * PROW + c4 * 4) = sv[i];
    }
  };

  // ---- prologue: start panel(b) stream, load A fragments into registers
  stage_issue(b);
  bf8 af[16];
  {
    const float4* ar4 =
        (const float4*)(eps + (size_t)(16 * wsg + lcol) * DT + 8 * q);
    #pragma unroll 1
    for (int c = 0; c < 4; ++c) {  // chunks of 4 K-steps (32 regs in flight)
      float4 x[4], y[4];
      #pragma unroll
      for (int i = 0; i < 4; ++i) {
        x[i] = ar4[(c * 4 + i) * 8];
        y[i] = ar4[(c * 4 + i) * 8 + 1];
      }
      #pragma unroll
      for (int i = 0; i < 4; ++i) af[c * 4 + i] = cvt8(x[i], y[i]);
    }
  }
  stage_write(Bp[0]);
  __syncthreads();

  const int rounds = (b < 16) ? 9 : 8;  // NP = 2064 = 256*8 + 16
  #pragma unroll 1
  for (int js = 0; js < rounds; ++js) {
    const int p = b + 256 * js;
    const bool isz = (p < 16);
    const float* cur = Bp[js & 1];
    float* nxt = Bp[(js + 1) & 1];
    const bool have_next = (p + 256 < NP);
    const int col0 = 32 * p + 16 * grp;
    const int colL = col0 + lcol;

    // diag loads first (their wait never drains the stage stream)
    float4 dbx, dby, dax, day;
    if (!isz) {
      const int nB = p - 16;  // 32x32 Ly block
      const float* pb = Ly + ((size_t)nB * 32 + 16 * grp + lcol) * 32 + 8 * q;
      dbx = *(const float4*)pb; dby = *(const float4*)(pb + 4);
      const float* pa =
          eps + (size_t)(16 * wsg + lcol) * DT + DZ + (size_t)nB * 32 + 8 * q;
      dax = *(const float4*)pa; day = *(const float4*)(pa + 4);
    }
    if (have_next) stage_issue(p + 256);

    // ---- compute: LDS + VALU + MFMA only
    f4 acc = f4{0.f, 0.f, 0.f, 0.f};
    const float* prow = cur + (16 * grp + lcol) * PROW + 8 * q;
    if (isz) {
      #pragma unroll
      for (int kk = 0; kk < 16; ++kk) {
        const float4 x = *(const float4*)(prow + kk * 32);
        const float4 y = *(const float4*)(prow + kk * 32 + 4);
        const bf8 bf = cvt8_tril(x, y, kk * 32 + 8 * q, colL);
        acc = __builtin_amdgcn_mfma_f32_16x16x32_bf16(af[kk], bf, acc, 0, 0, 0);
      }
    } else {
      #pragma unroll
      for (int kk = 0; kk < 16; ++kk) {
        const float4 x = *(const float4*)(prow + kk * 32);
        const float4 y = *(const float4*)(prow + kk * 32 + 4);
        const bf8 bf = cvt8(x, y);
        acc = __builtin_amdgcn_mfma_f32_16x16x32_bf16(af[kk], bf, acc, 0, 0, 0);
      }
      // block-diag einsum step
      const bf8 afd = cvt8(dax, day);
      const bf8 dbf = cvt8_tril(dbx, dby, 8 * q, 16 * grp + lcol);
      acc = __builtin_amdgcn_mfma_f32_16x16x32_bf16(afd, dbf, acc, 0, 0, 0);
    }

    // ---- epilogue for this pair's 16 cols x 16 samples per wave
    const float mval = mv[colL];
    #pragma unroll
    for (int rr = 0; rr < 4; ++rr) {
      out[(size_t)(16 * wsg + 4 * q + rr) * DT + colL] = acc[rr] + mval;
    }

    if (have_next) stage_write(nxt);  // waits only the stage loads (landed under compute)
    __syncthreads();
  }
}

extern "C" void kernel_launch(void* const* d_in, const int* in_sizes, int n_in,
                              void* d_out, int out_size, void* d_ws, size_t ws_size,
                              hipStream_t stream) {
  const float* m   = (const float*)d_in[0];
  const float* Lz  = (const float*)d_in[1];
  const float* Ly  = (const float*)d_in[2];
  const float* Lyz = (const float*)d_in[3];
  const float* eps = (const float*)d_in[4];
  float* out = (float*)d_out;
  sv_kernel<<<dim3(256), dim3(1024), 0, stream>>>(m, Lz, Ly, Lyz, eps, out);
}

// Round 12
// 88.239 us; speedup vs baseline: 2.1994x; 2.1994x over previous
//
#include <hip/hip_runtime.h>

#define DZ 512
#define DT 66048
#define NTILE 2064  // 32-col tiles
#define SV_JITTER 1e-4f

typedef __attribute__((ext_vector_type(8))) short bf8;
typedef __attribute__((ext_vector_type(4))) float f4;
typedef __attribute__((address_space(1))) const void glb_t;
typedef __attribute__((address_space(3))) void lds_t;

__device__ __forceinline__ short f2bf(float f) {
  unsigned u = __builtin_bit_cast(unsigned, f);
  return (short)((u + 0x7FFFu + ((u >> 16) & 1u)) >> 16);
}

__device__ __forceinline__ bf8 cvt8(float4 a, float4 b) {
  bf8 r = { f2bf(a.x), f2bf(a.y), f2bf(a.z), f2bf(a.w),
            f2bf(b.x), f2bf(b.y), f2bf(b.z), f2bf(b.w) };
  return r;
}

// tril/jitter cvt: element t has k-index kbase+t
__device__ __forceinline__ bf8 cvt8_tril(float4 x, float4 y, int kbase, int diag) {
  float v[8] = {x.x, x.y, x.z, x.w, y.x, y.y, y.z, y.w};
  bf8 r;
  #pragma unroll
  for (int t = 0; t < 8; ++t) {
    int k = kbase + t;
    float val = (k < diag) ? v[t] : ((k == diag) ? v[t] + SV_JITTER : 0.f);
    r[t] = f2bf(val);
  }
  return r;
}

// 256 blocks (1/CU) x 512 threads (8 waves, VGPR cap 256 via (512,2)).
// Wave wv = sample group (rows 16wv..+15); af[16] = its eps_z A-fragments in
// REGISTERS (64 VGPR, static fill). Per round the block's 32-col tile panel
// (contiguous 64KB of Lyz/Lz) is staged via global_load_lds directly into
// MFMA-frag-layout fp32 LDS (zero staging regs, linear lane x 16B dest,
// pre-swizzled global source); double-buffered. Compute: lane-linear
// ds_read_b128 (conflict-free) + cvt + 2 MFMA per K-step. Stage(r+1) issues
// before compute(r); the round barrier's implicit vmcnt(0) = panel ready.
// acc layout per mfma_f32_16x16x32_bf16: col=lane&15, row=4*(lane>>4)+reg.
__global__ __launch_bounds__(512, 2)
void sv_kernel(const float* __restrict__ mv, const float* __restrict__ Lz,
               const float* __restrict__ Ly, const float* __restrict__ Lyz,
               const float* __restrict__ eps, float* __restrict__ out) {
  // panel float index: g*8192 + kk*512 + h*256 + 4*lane  holds
  // L[col0+16g+(lane&15)][32kk + 8*(lane>>4) + 4h .. +3]
  __shared__ float Bp[2][16384];  // 2 x 64 KB

  const int tid = threadIdx.x;
  const int lane = tid & 63;
  const int wv = tid >> 6;  // 0..7 = sample group
  const int lcol = lane & 15;
  const int q = lane >> 4;
  const int b = blockIdx.x;

  // wave's staging share: sub-panel g = wv>>2, kk in [(wv&3)*4, +4), h 0..1
  auto stage_issue = [&](int T, int buf) {
    const int g = wv >> 2;
    const int col0 = 32 * T + 16 * g;
    const float* Ls = (T < 16) ? (Lz + (size_t)col0 * DZ)
                               : (Lyz + (size_t)(col0 - DZ) * DZ);
    const float* src = Ls + (size_t)lcol * DZ + 8 * q;  // lane's row+koct base
    float* dst = &Bp[buf][g * 8192];
    #pragma unroll
    for (int i = 0; i < 4; ++i) {
      const int kk = (wv & 3) * 4 + i;
      __builtin_amdgcn_global_load_lds((glb_t*)(src + 32 * kk),
                                       (lds_t*)(dst + kk * 512), 16, 0, 0);
      __builtin_amdgcn_global_load_lds((glb_t*)(src + 32 * kk + 4),
                                       (lds_t*)(dst + kk * 512 + 256), 16, 0, 0);
    }
  };

  // ---- prologue: issue tile(b) panel stream; fill af[16] (STATIC unroll)
  stage_issue(b, 0);
  bf8 af[16];
  {
    const float* ar = eps + (size_t)(16 * wv + lcol) * DT + 8 * q;
    #pragma unroll
    for (int kk = 0; kk < 16; ++kk) {
      const float4 x = *(const float4*)(ar + 32 * kk);
      const float4 y = *(const float4*)(ar + 32 * kk + 4);
      af[kk] = cvt8(x, y);
    }
  }
  __syncthreads();  // drains this wave's stage loads (vmcnt 0) + barrier

  #pragma unroll 1
  for (int r = 0; r < 9; ++r) {
    const int T = r * 256 + b;
    if (T >= NTILE) break;
    const bool isz = (T < 16);
    const int Tn = T + 256;
    if (Tn < NTILE) stage_issue(Tn, (r + 1) & 1);

    // diag-step loads (y tiles): issued early, land under compute
    float4 dax, day, db0x, db0y, db1x, db1y;
    if (!isz) {
      const int nb = T - 16;  // 32x32 Ly block
      const float* pa =
          eps + (size_t)(16 * wv + lcol) * DT + DZ + (size_t)nb * 32 + 8 * q;
      dax = *(const float4*)pa; day = *(const float4*)(pa + 4);
      const float* pb0 = Ly + ((size_t)nb * 32 + lcol) * 32 + 8 * q;
      db0x = *(const float4*)pb0; db0y = *(const float4*)(pb0 + 4);
      const float* pb1 = Ly + ((size_t)nb * 32 + 16 + lcol) * 32 + 8 * q;
      db1x = *(const float4*)pb1; db1y = *(const float4*)(pb1 + 4);
    }

    // ---- compute from Bp[r&1]: LDS + VALU + MFMA only
    const float* pan = &Bp[r & 1][0];
    f4 acc0 = f4{0.f, 0.f, 0.f, 0.f};
    f4 acc1 = f4{0.f, 0.f, 0.f, 0.f};
    const int c0 = 32 * T + lcol;
    if (isz) {
      #pragma unroll
      for (int kk = 0; kk < 16; ++kk) {
        const float4 x0 = *(const float4*)(pan + kk * 512 + 4 * lane);
        const float4 y0 = *(const float4*)(pan + kk * 512 + 256 + 4 * lane);
        const float4 x1 = *(const float4*)(pan + 8192 + kk * 512 + 4 * lane);
        const float4 y1 = *(const float4*)(pan + 8192 + kk * 512 + 256 + 4 * lane);
        const bf8 b0 = cvt8_tril(x0, y0, 32 * kk + 8 * q, c0);
        const bf8 b1 = cvt8_tril(x1, y1, 32 * kk + 8 * q, c0 + 16);
        acc0 = __builtin_amdgcn_mfma_f32_16x16x32_bf16(af[kk], b0, acc0, 0, 0, 0);
        acc1 = __builtin_amdgcn_mfma_f32_16x16x32_bf16(af[kk], b1, acc1, 0, 0, 0);
      }
    } else {
      #pragma unroll
      for (int kk = 0; kk < 16; ++kk) {
        const float4 x0 = *(const float4*)(pan + kk * 512 + 4 * lane);
        const float4 y0 = *(const float4*)(pan + kk * 512 + 256 + 4 * lane);
        const float4 x1 = *(const float4*)(pan + 8192 + kk * 512 + 4 * lane);
        const float4 y1 = *(const float4*)(pan + 8192 + kk * 512 + 256 + 4 * lane);
        const bf8 b0 = cvt8(x0, y0);
        const bf8 b1 = cvt8(x1, y1);
        acc0 = __builtin_amdgcn_mfma_f32_16x16x32_bf16(af[kk], b0, acc0, 0, 0, 0);
        acc1 = __builtin_amdgcn_mfma_f32_16x16x32_bf16(af[kk], b1, acc1, 0, 0, 0);
      }
      // block-diag einsum step
      const bf8 afd = cvt8(dax, day);
      const bf8 dbf0 = cvt8_tril(db0x, db0y, 8 * q, lcol);
      const bf8 dbf1 = cvt8_tril(db1x, db1y, 8 * q, 16 + lcol);
      acc0 = __builtin_amdgcn_mfma_f32_16x16x32_bf16(afd, dbf0, acc0, 0, 0, 0);
      acc1 = __builtin_amdgcn_mfma_f32_16x16x32_bf16(afd, dbf1, acc1, 0, 0, 0);
    }

    // ---- epilogue: both 64B halves of each 128B out line from this wave
    {
      const float m0 = mv[c0], m1 = mv[c0 + 16];
      #pragma unroll
      for (int rr = 0; rr < 4; ++rr) {
        const size_t rowoff = (size_t)(16 * wv + 4 * q + rr) * DT;
        out[rowoff + c0] = acc0[rr] + m0;
        out[rowoff + c0 + 16] = acc1[rr] + m1;
      }
    }

    __syncthreads();  // next panel complete + old buffer free
  }
}

extern "C" void kernel_launch(void* const* d_in, const int* in_sizes, int n_in,
                              void* d_out, int out_size, void* d_ws, size_t ws_size,
                              hipStream_t stream) {
  const float* m   = (const float*)d_in[0];
  const float* Lz  = (const float*)d_in[1];
  const float* Ly  = (const float*)d_in[2];
  const float* Lyz = (const float*)d_in[3];
  const float* eps = (const float*)d_in[4];
  float* out = (float*)d_out;
  sv_kernel<<<dim3(256), dim3(512), 0, stream>>>(m, Lz, Ly, Lyz, eps, out);
}